// Round 1
// baseline (1038.094 us; speedup 1.0000x reference)
//
#include <hip/hip_runtime.h>

#define NHD 16
#define DHD 64
#define SEQL 1024
#define DM 1024
#define NB 4

// ---------------- tiled f32 GEMM ----------------
// BT=true : C = X * B^T, B is (N,K) row-major (weight W[e][d])
// BT=false: C = X * B,   B is (K,N) row-major, per-1024-row batch offset bvstride
// LAYOUT 0: scatter to head layout [b][h][s][dh]  (r = b*1024+s, e = h*64+dh)
// LAYOUT 2: plain row-major C[r][n]
template<bool BT, int LAYOUT>
__global__ __launch_bounds__(256)
void gemm_k(const float* __restrict__ X, const float* __restrict__ Bm,
            float* __restrict__ C, int M, int N, int K, int bvstride)
{
    __shared__ float Xs[16][132];
    __shared__ float Bs[16][132];
    const int tid = threadIdx.x;
    const int r0 = blockIdx.y * 128;
    const int n0 = blockIdx.x * 128;
    const float* Bp = Bm + (BT ? (size_t)0 : (size_t)(r0 >> 10) * (size_t)bvstride);

    float acc[8][8];
#pragma unroll
    for (int i = 0; i < 8; ++i)
#pragma unroll
        for (int j = 0; j < 8; ++j) acc[i][j] = 0.f;

    const int ty = tid >> 2;   // 0..63
    const int tx = tid & 3;    // 0..3
    const int tm = tid >> 4;   // 0..15
    const int tn = tid & 15;   // 0..15

    for (int k0 = 0; k0 < K; k0 += 16) {
        __syncthreads();
        {   // stage X transposed: Xs[dk][m]
            float4 x0 = *(const float4*)&X[(size_t)(r0 + ty) * K + k0 + tx * 4];
            float4 x1 = *(const float4*)&X[(size_t)(r0 + ty + 64) * K + k0 + tx * 4];
            Xs[tx*4+0][ty] = x0.x; Xs[tx*4+1][ty] = x0.y; Xs[tx*4+2][ty] = x0.z; Xs[tx*4+3][ty] = x0.w;
            Xs[tx*4+0][ty+64] = x1.x; Xs[tx*4+1][ty+64] = x1.y; Xs[tx*4+2][ty+64] = x1.z; Xs[tx*4+3][ty+64] = x1.w;
        }
        if (BT) {   // stage W transposed: Bs[dk][e]
            float4 w0 = *(const float4*)&Bp[(size_t)(n0 + ty) * K + k0 + tx * 4];
            float4 w1 = *(const float4*)&Bp[(size_t)(n0 + ty + 64) * K + k0 + tx * 4];
            Bs[tx*4+0][ty] = w0.x; Bs[tx*4+1][ty] = w0.y; Bs[tx*4+2][ty] = w0.z; Bs[tx*4+3][ty] = w0.w;
            Bs[tx*4+0][ty+64] = w1.x; Bs[tx*4+1][ty+64] = w1.y; Bs[tx*4+2][ty+64] = w1.z; Bs[tx*4+3][ty+64] = w1.w;
        } else {    // stage V direct: Bs[dk][n]
            const int dk = tid >> 5;   // 0..7
            const int nx = tid & 31;   // 0..31
            float4 v0 = *(const float4*)&Bp[(size_t)(k0 + dk) * N + n0 + nx * 4];
            float4 v1 = *(const float4*)&Bp[(size_t)(k0 + dk + 8) * N + n0 + nx * 4];
            *(float4*)&Bs[dk][nx*4]   = v0;
            *(float4*)&Bs[dk+8][nx*4] = v1;
        }
        __syncthreads();
#pragma unroll
        for (int dk = 0; dk < 16; ++dk) {
            float4 a0 = *(const float4*)&Xs[dk][tm*8];
            float4 a1 = *(const float4*)&Xs[dk][tm*8+4];
            float4 b0 = *(const float4*)&Bs[dk][tn*8];
            float4 b1 = *(const float4*)&Bs[dk][tn*8+4];
            float av[8] = {a0.x,a0.y,a0.z,a0.w,a1.x,a1.y,a1.z,a1.w};
            float bv[8] = {b0.x,b0.y,b0.z,b0.w,b1.x,b1.y,b1.z,b1.w};
#pragma unroll
            for (int i = 0; i < 8; ++i)
#pragma unroll
                for (int j = 0; j < 8; ++j) acc[i][j] += av[i]*bv[j];
        }
    }

#pragma unroll
    for (int i = 0; i < 8; ++i) {
        const int r = r0 + tm*8 + i;
        float4 o0 = make_float4(acc[i][0],acc[i][1],acc[i][2],acc[i][3]);
        float4 o1 = make_float4(acc[i][4],acc[i][5],acc[i][6],acc[i][7]);
        if (LAYOUT == 2) {
            float* dst = C + (size_t)r * N + n0 + tn*8;
            *(float4*)dst = o0; *(float4*)(dst+4) = o1;
        } else {
            const int bb = r >> 10, s = r & 1023;
            const int e0 = n0 + tn*8;
            const int h = e0 >> 6, dh0 = e0 & 63;
            float* dst = C + (((size_t)(bb*NHD + h) * SEQL + s) * DHD + dh0);
            *(float4*)dst = o0; *(float4*)(dst+4) = o1;
        }
    }
}

// ---------------- fused scores + softmax + cum-threshold + head-mean ----------------
// grid: B * (SEQL/8) blocks, 512 threads (8 waves). Wave w owns q-row s0+w.
// Per head: stage K chunk [64d][128k] in LDS, accumulate 16 scores/lane (k = ch*128 + 2*l + {0,1}).
// Cum-threshold via 22-step bisection on the value axis (no sort):
//   zero element iff S_le(s_i) < 0.1  <=>  s_i <= lo_final.
__global__ __launch_bounds__(512)
void attn_k(const float* __restrict__ qh, const float* __restrict__ kh,
            const int* __restrict__ kmask, float* __restrict__ attn)
{
    __shared__ float kch[64][128];
    __shared__ float qs[512];
    __shared__ float mneg[1024];
    const int tid = threadIdx.x;
    const int b  = blockIdx.x >> 7;
    const int s0 = (blockIdx.x & 127) * 8;
    const int w  = tid >> 6;
    const int l  = tid & 63;

    for (int i = tid; i < 1024; i += 512)
        mneg[i] = (kmask[b * 1024 + i] > 0) ? 0.f : -3.4028235e38f;

    float racc[16];
#pragma unroll
    for (int j = 0; j < 16; ++j) racc[j] = 0.f;

    for (int h = 0; h < NHD; ++h) {
        __syncthreads();   // guard qs/kch reuse from previous head (also covers mneg init)
        qs[tid] = qh[((size_t)((b*NHD + h) * SEQL) + s0 + (tid >> 6)) * DHD + (tid & 63)];

        float sc[16];
#pragma unroll
        for (int j = 0; j < 16; ++j) sc[j] = 0.f;

#pragma unroll
        for (int ch = 0; ch < 8; ++ch) {
            __syncthreads();
            {   // stage K chunk transposed: kch[d][kk]
                const int kk = tid & 127;
                const int dg = tid >> 7;   // 0..3
                const float* kp = &kh[((size_t)((b*NHD + h) * SEQL) + ch*128 + kk) * DHD];
#pragma unroll
                for (int p = 0; p < 4; ++p) {
                    const int d0 = (p*4 + dg) * 4;
                    float4 kv = *(const float4*)&kp[d0];
                    kch[d0+0][kk] = kv.x; kch[d0+1][kk] = kv.y;
                    kch[d0+2][kk] = kv.z; kch[d0+3][kk] = kv.w;
                }
            }
            __syncthreads();
#pragma unroll
            for (int d = 0; d < 64; d += 4) {
                float4 qv4 = *(const float4*)&qs[w*64 + d];
                float qa[4] = {qv4.x, qv4.y, qv4.z, qv4.w};
#pragma unroll
                for (int dd = 0; dd < 4; ++dd) {
                    float2 kv = *(const float2*)&kch[d+dd][2*l];
                    sc[ch*2]   += qa[dd] * kv.x;
                    sc[ch*2+1] += qa[dd] * kv.y;
                }
            }
        }

        // scale + mask + softmax
        float mx = -3.4028235e38f;
#pragma unroll
        for (int j = 0; j < 16; ++j) {
            sc[j] = sc[j] * 0.125f + mneg[(j>>1)*128 + 2*l + (j&1)];
            mx = fmaxf(mx, sc[j]);
        }
#pragma unroll
        for (int off = 32; off > 0; off >>= 1) mx = fmaxf(mx, __shfl_xor(mx, off));
        float Z = 0.f;
#pragma unroll
        for (int j = 0; j < 16; ++j) { sc[j] = __expf(sc[j] - mx); Z += sc[j]; }
#pragma unroll
        for (int off = 32; off > 0; off >>= 1) Z += __shfl_xor(Z, off);
        const float invZ = 1.f / Z;
#pragma unroll
        for (int j = 0; j < 16; ++j) sc[j] *= invZ;

        // bisection for the cumulative-mass cutoff: invariant S_le(lo) < 0.1 <= S_le(hi)
        float lo = 0.f, hi = invZ;   // max softmax value is exactly invZ
        for (int it = 0; it < 22; ++it) {
            const float c = 0.5f * (lo + hi);
            float t = 0.f;
#pragma unroll
            for (int j = 0; j < 16; ++j) t += (sc[j] <= c) ? sc[j] : 0.f;
#pragma unroll
            for (int off = 32; off > 0; off >>= 1) t += __shfl_xor(t, off);
            if (t < 0.1f) lo = c; else hi = c;   // t bit-identical across lanes (symmetric butterfly)
        }

        float A = 0.f;
#pragma unroll
        for (int j = 0; j < 16; ++j) A += (sc[j] > lo) ? sc[j] : 0.f;
#pragma unroll
        for (int off = 32; off > 0; off >>= 1) A += __shfl_xor(A, off);
        const float rn = 1.f / (A + 1e-7f);
#pragma unroll
        for (int j = 0; j < 16; ++j) racc[j] += ((sc[j] > lo) ? sc[j] : 0.f) * rn;
    }

    // head mean -> attn
#pragma unroll
    for (int ch = 0; ch < 8; ++ch) {
        float2 o;
        o.x = racc[ch*2]   * 0.0625f;
        o.y = racc[ch*2+1] * 0.0625f;
        *(float2*)&attn[((size_t)(b*SEQL) + s0 + w) * SEQL + ch*128 + 2*l] = o;
    }
}

extern "C" void kernel_launch(void* const* d_in, const int* in_sizes, int n_in,
                              void* d_out, int out_size, void* d_ws, size_t ws_size,
                              hipStream_t stream) {
    const float* q  = (const float*)d_in[0];
    const float* k  = (const float*)d_in[1];
    const float* v  = (const float*)d_in[2];
    const float* Wq = (const float*)d_in[3];
    const float* Wk = (const float*)d_in[4];
    const int* kmask = (const int*)d_in[5];

    float* out  = (float*)d_out;                       // (4,1024,1024)
    float* attn = out + (size_t)NB * SEQL * SEQL;      // (4,1024,1024)
    float* qh = out;            // park qh in out-region; overwritten by final GEMM
    float* kh = (float*)d_ws;   // 16.8 MB scratch

    dim3 g(8, 32), blk(256);
    gemm_k<true, 0><<<g, blk, 0, stream>>>(q, Wq, qh, NB*SEQL, DM, DM, 0);
    gemm_k<true, 0><<<g, blk, 0, stream>>>(k, Wk, kh, NB*SEQL, DM, DM, 0);
    attn_k<<<dim3(NB * (SEQL/8)), dim3(512), 0, stream>>>(qh, kh, kmask, attn);
    gemm_k<false, 2><<<g, blk, 0, stream>>>(attn, v, out, NB*SEQL, DM, SEQL, SEQL*DM);
}

// Round 2
// 777.839 us; speedup vs baseline: 1.3346x; 1.3346x over previous
//
#include <hip/hip_runtime.h>

typedef unsigned short u16;
typedef unsigned int u32;
typedef __attribute__((ext_vector_type(8))) short bf16x8;
typedef __attribute__((ext_vector_type(4))) float f32x4;

#define MFMA __builtin_amdgcn_mfma_f32_16x16x32_bf16

__device__ __forceinline__ u16 f2bf(float x) {
    union { float f; u32 u; } a; a.f = x;
    return (u16)((a.u + 0x7fffu + ((a.u >> 16) & 1u)) >> 16);
}
__device__ __forceinline__ float bf2f(u16 h) {
    union { u32 u; float f; } a; a.u = ((u32)h) << 16;
    return a.f;
}

// Stage a 128x64 f32 tile into hi/lo bf16 LDS tiles, rows 128B, 16B-chunk XOR swizzle.
__device__ __forceinline__ void stage_f32(const float* __restrict__ src, int row0, int k0,
                                          char* Lh, char* Ll, int tid)
{
    const int rb = tid >> 4;
    const int c4 = tid & 15;
#pragma unroll
    for (int i = 0; i < 8; ++i) {
        const int row = rb + i * 16;
        const float4 x = *(const float4*)&src[(size_t)(row0 + row) * 1024 + k0 + c4 * 4];
        u16 h0 = f2bf(x.x), h1 = f2bf(x.y), h2 = f2bf(x.z), h3 = f2bf(x.w);
        u16 l0 = f2bf(x.x - bf2f(h0)), l1 = f2bf(x.y - bf2f(h1));
        u16 l2 = f2bf(x.z - bf2f(h2)), l3 = f2bf(x.w - bf2f(h3));
        const int byte = row * 128 + (((((c4 >> 1) << 4)) ^ ((row & 7) << 4)) | ((c4 & 1) << 3));
        *(uint2*)&Lh[byte] = make_uint2((u32)h0 | ((u32)h1 << 16), (u32)h2 | ((u32)h3 << 16));
        *(uint2*)&Ll[byte] = make_uint2((u32)l0 | ((u32)l1 << 16), (u32)l2 | ((u32)l3 << 16));
    }
}

// Read one 16x32 MFMA A/B fragment (8 bf16/lane) from a swizzled [128][64]bf16 LDS tile.
__device__ __forceinline__ bf16x8 ldfrag(const char* L, int row, int kk, int lg)
{
    const int cb = (kk * 64 + (lg << 4)) ^ ((row & 7) << 4);
    return *(const bf16x8*)&L[row * 128 + cb];
}

// Split-bf16 MFMA GEMM: D[m][n] = sum_k A[m][k]*B[n][k], f32 inputs, f32-accurate (hh+hl+lh).
// MODE 0: proj — C = hi/lo bf16 pair in head layout [b][h][s][dh] with m=e, n=(b,s).
// MODE 2: out  — C = f32 row-major [m][n]; B batched per 1024 m-rows (vt[b][n][k]).
template<int MODE>
__global__ __launch_bounds__(256)
void gemmT(const float* __restrict__ A, const float* __restrict__ B,
           void* __restrict__ C0, void* __restrict__ C1)
{
    __shared__ __align__(16) char Ah[16384], Bh[16384], Al[16384], Bl[16384];
    const int tid = threadIdx.x;
    const int m0 = blockIdx.y * 128;
    const int n0 = blockIdx.x * 128;
    const int w = tid >> 6, l = tid & 63;
    const int wr = (w >> 1) * 64, wc = (w & 1) * 64;
    const int lm = l & 15, lg = l >> 4;
    const float* Bp = B + (MODE == 2 ? ((size_t)(m0 >> 10) << 20) : (size_t)0);

    f32x4 acc[4][4];
#pragma unroll
    for (int a = 0; a < 4; ++a)
#pragma unroll
        for (int bq = 0; bq < 4; ++bq) acc[a][bq] = (f32x4){0.f, 0.f, 0.f, 0.f};

    for (int k0 = 0; k0 < 1024; k0 += 64) {
        __syncthreads();
        stage_f32(A,  m0, k0, Ah, Al, tid);
        stage_f32(Bp, n0, k0, Bh, Bl, tid);
        __syncthreads();
#pragma unroll
        for (int kk = 0; kk < 2; ++kk) {
            bf16x8 aH[4], aL[4], bH[4], bL[4];
#pragma unroll
            for (int mi = 0; mi < 4; ++mi) {
                aH[mi] = ldfrag(Ah, wr + mi * 16 + lm, kk, lg);
                aL[mi] = ldfrag(Al, wr + mi * 16 + lm, kk, lg);
            }
#pragma unroll
            for (int ni = 0; ni < 4; ++ni) {
                bH[ni] = ldfrag(Bh, wc + ni * 16 + lm, kk, lg);
                bL[ni] = ldfrag(Bl, wc + ni * 16 + lm, kk, lg);
            }
#pragma unroll
            for (int mi = 0; mi < 4; ++mi)
#pragma unroll
                for (int ni = 0; ni < 4; ++ni) {
                    acc[mi][ni] = MFMA(aH[mi], bH[ni], acc[mi][ni], 0, 0, 0);
                    acc[mi][ni] = MFMA(aH[mi], bL[ni], acc[mi][ni], 0, 0, 0);
                    acc[mi][ni] = MFMA(aL[mi], bH[ni], acc[mi][ni], 0, 0, 0);
                }
        }
    }

#pragma unroll
    for (int mi = 0; mi < 4; ++mi)
#pragma unroll
        for (int ni = 0; ni < 4; ++ni) {
            const int m = m0 + wr + mi * 16 + lg * 4;   // 4 consecutive m via i
            const int n = n0 + wc + ni * 16 + lm;
            if (MODE == 0) {
                const int bb = n >> 10, s = n & 1023;
                const int h = m >> 6, dh = m & 63;
                const size_t base = (((size_t)(bb * 16 + h) << 10) + s) * 64 + dh;
                u16 hh[4], ll[4];
#pragma unroll
                for (int i = 0; i < 4; ++i) {
                    hh[i] = f2bf(acc[mi][ni][i]);
                    ll[i] = f2bf(acc[mi][ni][i] - bf2f(hh[i]));
                }
                *(uint2*)&((u16*)C0)[base] = make_uint2((u32)hh[0] | ((u32)hh[1] << 16),
                                                        (u32)hh[2] | ((u32)hh[3] << 16));
                *(uint2*)&((u16*)C1)[base] = make_uint2((u32)ll[0] | ((u32)ll[1] << 16),
                                                        (u32)ll[2] | ((u32)ll[3] << 16));
            } else {
#pragma unroll
                for (int i = 0; i < 4; ++i)
                    ((float*)C0)[(size_t)(m + i) * 1024 + n] = acc[mi][ni][i];
            }
        }
}

// Fused scores (split-bf16 MFMA, S^T) + softmax + cumulative-threshold bisection + head-mean.
// Block = (b, 16 q-rows), 8 waves. Wave w: MFMA kv-slice [w*128,+128) x 16 q; then rows 2w,2w+1.
__global__ __launch_bounds__(512)
void attn2_k(const u16* __restrict__ qhh, const u16* __restrict__ qhl,
             const u16* __restrict__ khh, const u16* __restrict__ khl,
             const int* __restrict__ kmask, float* __restrict__ attn)
{
    __shared__ __align__(16) float S[16][1028];
    __shared__ __align__(16) float mneg[1024];
    const int tid = threadIdx.x;
    const int b = blockIdx.x >> 6;
    const int q0 = (blockIdx.x & 63) << 4;
    const int w = tid >> 6, l = tid & 63;
    const int lm = l & 15, lg = l >> 4;

    for (int i = tid; i < 1024; i += 512)
        mneg[i] = (kmask[(b << 10) + i] > 0) ? 0.f : -3.0e38f;

    float racc0[16], racc1[16];
#pragma unroll
    for (int j = 0; j < 16; ++j) { racc0[j] = 0.f; racc1[j] = 0.f; }

    for (int h = 0; h < 16; ++h) {
        const size_t hb = (size_t)((b << 4) + h) << 10;
        const size_t qoff = (hb + q0 + lm) * 64 + (lg << 3);
        const bf16x8 bh0 = *(const bf16x8*)&qhh[qoff];
        const bf16x8 bh1 = *(const bf16x8*)&qhh[qoff + 32];
        const bf16x8 bl0 = *(const bf16x8*)&qhl[qoff];
        const bf16x8 bl1 = *(const bf16x8*)&qhl[qoff + 32];

        f32x4 acc[8];
#pragma unroll
        for (int mi = 0; mi < 8; ++mi) acc[mi] = (f32x4){0.f, 0.f, 0.f, 0.f};

        const int kvb = w << 7;
#pragma unroll
        for (int mi = 0; mi < 8; ++mi) {
            const size_t aoff = (hb + kvb + (mi << 4) + lm) * 64 + (lg << 3);
            const bf16x8 ah0 = *(const bf16x8*)&khh[aoff];
            const bf16x8 ah1 = *(const bf16x8*)&khh[aoff + 32];
            const bf16x8 al0 = *(const bf16x8*)&khl[aoff];
            const bf16x8 al1 = *(const bf16x8*)&khl[aoff + 32];
            acc[mi] = MFMA(ah0, bh0, acc[mi], 0, 0, 0);
            acc[mi] = MFMA(ah0, bl0, acc[mi], 0, 0, 0);
            acc[mi] = MFMA(al0, bh0, acc[mi], 0, 0, 0);
            acc[mi] = MFMA(ah1, bh1, acc[mi], 0, 0, 0);
            acc[mi] = MFMA(ah1, bl1, acc[mi], 0, 0, 0);
            acc[mi] = MFMA(al1, bh1, acc[mi], 0, 0, 0);
        }
        __syncthreads();   // previous head's softmax reads finished
#pragma unroll
        for (int mi = 0; mi < 8; ++mi)
            *(f32x4*)&S[lm][kvb + (mi << 4) + (lg << 2)] = acc[mi];
        __syncthreads();

        // softmax + bisection for rows 2w, 2w+1 (interleaved for latency hiding)
        float sa[16], sb[16];
#pragma unroll
        for (int jj = 0; jj < 4; ++jj) {
            const f32x4 va = *(const f32x4*)&S[2 * w][jj * 256 + l * 4];
            const f32x4 vb = *(const f32x4*)&S[2 * w + 1][jj * 256 + l * 4];
            const f32x4 vm = *(const f32x4*)&mneg[jj * 256 + l * 4];
#pragma unroll
            for (int ii = 0; ii < 4; ++ii) {
                sa[jj * 4 + ii] = va[ii] * 0.125f + vm[ii];
                sb[jj * 4 + ii] = vb[ii] * 0.125f + vm[ii];
            }
        }
        float ma = -3.0e38f, mb = -3.0e38f;
#pragma unroll
        for (int j = 0; j < 16; ++j) { ma = fmaxf(ma, sa[j]); mb = fmaxf(mb, sb[j]); }
#pragma unroll
        for (int off = 32; off; off >>= 1) { ma = fmaxf(ma, __shfl_xor(ma, off)); mb = fmaxf(mb, __shfl_xor(mb, off)); }
        float Za = 0.f, Zb = 0.f;
#pragma unroll
        for (int j = 0; j < 16; ++j) {
            sa[j] = __expf(sa[j] - ma); Za += sa[j];
            sb[j] = __expf(sb[j] - mb); Zb += sb[j];
        }
#pragma unroll
        for (int off = 32; off; off >>= 1) { Za += __shfl_xor(Za, off); Zb += __shfl_xor(Zb, off); }

        // zero element iff S_le(e) < 0.1*Z; find cutoff by bisection on e in [0,1]
        const float tga = 0.1f * Za, tgb = 0.1f * Zb;
        float loa = 0.f, hia = 1.f, lob = 0.f, hib = 1.f;
        for (int it = 0; it < 18; ++it) {
            const float ca = 0.5f * (loa + hia), cb = 0.5f * (lob + hib);
            float ta = 0.f, tb = 0.f;
#pragma unroll
            for (int j = 0; j < 16; ++j) {
                ta += (sa[j] <= ca) ? sa[j] : 0.f;
                tb += (sb[j] <= cb) ? sb[j] : 0.f;
            }
#pragma unroll
            for (int off = 32; off; off >>= 1) { ta += __shfl_xor(ta, off); tb += __shfl_xor(tb, off); }
            if (ta < tga) loa = ca; else hia = ca;   // ta bit-identical across lanes
            if (tb < tgb) lob = cb; else hib = cb;
        }
        float Aa = 0.f, Ab = 0.f;
#pragma unroll
        for (int j = 0; j < 16; ++j) {
            Aa += (sa[j] > loa) ? sa[j] : 0.f;
            Ab += (sb[j] > lob) ? sb[j] : 0.f;
        }
#pragma unroll
        for (int off = 32; off; off >>= 1) { Aa += __shfl_xor(Aa, off); Ab += __shfl_xor(Ab, off); }
        const float rna = 1.f / (Aa + 1e-7f * Za);
        const float rnb = 1.f / (Ab + 1e-7f * Zb);
#pragma unroll
        for (int j = 0; j < 16; ++j) {
            racc0[j] += ((sa[j] > loa) ? sa[j] : 0.f) * rna;
            racc1[j] += ((sb[j] > lob) ? sb[j] : 0.f) * rnb;
        }
    }

#pragma unroll
    for (int jj = 0; jj < 4; ++jj) {
        f32x4 oa, ob;
#pragma unroll
        for (int ii = 0; ii < 4; ++ii) {
            oa[ii] = racc0[jj * 4 + ii] * 0.0625f;
            ob[ii] = racc1[jj * 4 + ii] * 0.0625f;
        }
        *(f32x4*)&attn[((size_t)(b << 10) + q0 + 2 * w) * 1024 + jj * 256 + l * 4] = oa;
        *(f32x4*)&attn[((size_t)(b << 10) + q0 + 2 * w + 1) * 1024 + jj * 256 + l * 4] = ob;
    }
}

// v [b][kv][d] f32 -> vt [b][d][kv] f32 (64x64 LDS tiles)
__global__ __launch_bounds__(256)
void vtT_k(const float* __restrict__ v, float* __restrict__ vt)
{
    __shared__ float T[64][65];
    const int b = blockIdx.z;
    const int kv0 = blockIdx.y << 6, d0 = blockIdx.x << 6;
    const int t = threadIdx.x;
    const int tr = t >> 4, tc = t & 15;
#pragma unroll
    for (int i = 0; i < 4; ++i) {
        const float4 x = *(const float4*)&v[(((size_t)b << 10) + kv0 + tr + i * 16) * 1024 + d0 + tc * 4];
        float* d = &T[tr + i * 16][tc * 4];
        d[0] = x.x; d[1] = x.y; d[2] = x.z; d[3] = x.w;
    }
    __syncthreads();
#pragma unroll
    for (int i = 0; i < 4; ++i) {
        const int dr = tr + i * 16;
        float4 o;
        o.x = T[tc * 4 + 0][dr]; o.y = T[tc * 4 + 1][dr];
        o.z = T[tc * 4 + 2][dr]; o.w = T[tc * 4 + 3][dr];
        *(float4*)&vt[(((size_t)b << 10) + d0 + dr) * 1024 + kv0 + tc * 4] = o;
    }
}

extern "C" void kernel_launch(void* const* d_in, const int* in_sizes, int n_in,
                              void* d_out, int out_size, void* d_ws, size_t ws_size,
                              hipStream_t stream) {
    const float* q  = (const float*)d_in[0];
    const float* k  = (const float*)d_in[1];
    const float* v  = (const float*)d_in[2];
    const float* Wq = (const float*)d_in[3];
    const float* Wk = (const float*)d_in[4];
    const int* kmask = (const int*)d_in[5];

    // d_out: [0,16.8MB) = qh hi/lo during attn, then final out; [16.8,33.6MB) = attn f32 (final)
    // d_ws : [0,16.8MB) = kh hi/lo during attn, then vt f32
    u16* qhh = (u16*)d_out;
    u16* qhl = qhh + 4194304;
    u16* khh = (u16*)d_ws;
    u16* khl = khh + 4194304;
    float* attn = (float*)d_out + 4194304;
    float* vt   = (float*)d_ws;
    float* out  = (float*)d_out;

    gemmT<0><<<dim3(32, 8), 256, 0, stream>>>(Wq, q, qhh, qhl);   // qh = q @ Wq^T (head layout)
    gemmT<0><<<dim3(32, 8), 256, 0, stream>>>(Wk, k, khh, khl);   // kh = k @ Wk^T
    attn2_k<<<dim3(256), dim3(512), 0, stream>>>(qhh, qhl, khh, khl, kmask, attn);
    vtT_k<<<dim3(16, 16, 4), 256, 0, stream>>>(v, vt);            // vt = v^T (kh dead now)
    gemmT<2><<<dim3(8, 32), 256, 0, stream>>>(attn, vt, out, nullptr);  // out = attn @ v
}

// Round 3
// 530.506 us; speedup vs baseline: 1.9568x; 1.4662x over previous
//
#include <hip/hip_runtime.h>

typedef unsigned short u16;
typedef unsigned int u32;
typedef __attribute__((ext_vector_type(8))) short bf16x8;
typedef __attribute__((ext_vector_type(4))) float f32x4;

#define MFMA __builtin_amdgcn_mfma_f32_16x16x32_bf16

__device__ __forceinline__ u16 f2bf(float x) {
    union { float f; u32 u; } a; a.f = x;
    return (u16)((a.u + 0x7fffu + ((a.u >> 16) & 1u)) >> 16);
}
__device__ __forceinline__ float bf2f(u16 h) {
    union { u32 u; float f; } a; a.u = ((u32)h) << 16;
    return a.f;
}

// Convert one float4 to hi/lo bf16 and store 8B each into swizzled LDS tile (rows 128B).
__device__ __forceinline__ void cvt_store(char* Lh, char* Ll, int row, int c4, float4 x) {
    u16 h0 = f2bf(x.x), h1 = f2bf(x.y), h2 = f2bf(x.z), h3 = f2bf(x.w);
    u16 l0 = f2bf(x.x - bf2f(h0)), l1 = f2bf(x.y - bf2f(h1));
    u16 l2 = f2bf(x.z - bf2f(h2)), l3 = f2bf(x.w - bf2f(h3));
    const int byte = row * 128 + ((((c4 >> 1) << 4) ^ ((row & 7) << 4)) | ((c4 & 1) << 3));
    *(uint2*)&Lh[byte] = make_uint2((u32)h0 | ((u32)h1 << 16), (u32)h2 | ((u32)h3 << 16));
    *(uint2*)&Ll[byte] = make_uint2((u32)l0 | ((u32)l1 << 16), (u32)l2 | ((u32)l3 << 16));
}

// Read one 16x32 MFMA fragment (8 bf16/lane) from a swizzled [rows][64]bf16 LDS tile.
__device__ __forceinline__ bf16x8 ldfrag(const char* L, int row, int kk, int lg) {
    const int cb = (kk * 64 + (lg << 4)) ^ ((row & 7) << 4);
    return *(const bf16x8*)&L[row * 128 + cb];
}

// Split-bf16 MFMA GEMM: D[m][n] = sum_k A[m][k]*B[n][k], f32 inputs, f32-accurate (hh+hl+lh).
// Tiles 64(m) x 128(n) x 64(k); 256 threads / 4 waves; wave tile 32x64.
// MODE 0: proj — C = hi/lo bf16 pair in head layout [b][h][s][dh] with m=e, n=(b,s).
// MODE 2: out  — C = f32 row-major [m][n]; B batched per 1024 m-rows (vt[b][n][k]).
template<int MODE>
__global__ __launch_bounds__(256, 3)
void gemmT(const float* __restrict__ A, const float* __restrict__ B,
           void* __restrict__ C0, void* __restrict__ C1)
{
    __shared__ __align__(16) char Ah[8192], Al[8192], Bh[16384], Bl[16384];
    const int tid = threadIdx.x;
    const int m0 = blockIdx.y * 64;
    const int n0 = blockIdx.x * 128;
    const int w = tid >> 6, l = tid & 63;
    const int wr = (w >> 1) * 32, wc = (w & 1) * 64;
    const int lm = l & 15, lg = l >> 4;
    const float* Bp = B + (MODE == 2 ? ((size_t)(m0 >> 10) << 20) : (size_t)0);

    f32x4 acc[2][4];
#pragma unroll
    for (int a = 0; a < 2; ++a)
#pragma unroll
        for (int bq = 0; bq < 4; ++bq) acc[a][bq] = (f32x4){0.f, 0.f, 0.f, 0.f};

    const int ar = tid >> 2, ac = tid & 3;   // A: 64 rows, 16 floats/thread
    const int br = tid >> 1, bc = tid & 1;   // B: 128 rows, 32 floats/thread

    for (int k0 = 0; k0 < 1024; k0 += 64) {
        __syncthreads();
        const float* As = &A[(size_t)(m0 + ar) * 1024 + k0 + ac * 16];
#pragma unroll
        for (int j = 0; j < 4; ++j) cvt_store(Ah, Al, ar, ac * 4 + j, *(const float4*)&As[j * 4]);
        const float* Bs = &Bp[(size_t)(n0 + br) * 1024 + k0 + bc * 32];
#pragma unroll
        for (int j = 0; j < 8; ++j) cvt_store(Bh, Bl, br, bc * 8 + j, *(const float4*)&Bs[j * 4]);
        __syncthreads();
#pragma unroll
        for (int kk = 0; kk < 2; ++kk) {
            bf16x8 aH[2], aL[2], bH[4], bL[4];
#pragma unroll
            for (int mi = 0; mi < 2; ++mi) {
                aH[mi] = ldfrag(Ah, wr + mi * 16 + lm, kk, lg);
                aL[mi] = ldfrag(Al, wr + mi * 16 + lm, kk, lg);
            }
#pragma unroll
            for (int ni = 0; ni < 4; ++ni) {
                bH[ni] = ldfrag(Bh, wc + ni * 16 + lm, kk, lg);
                bL[ni] = ldfrag(Bl, wc + ni * 16 + lm, kk, lg);
            }
#pragma unroll
            for (int mi = 0; mi < 2; ++mi)
#pragma unroll
                for (int ni = 0; ni < 4; ++ni) {
                    acc[mi][ni] = MFMA(aH[mi], bH[ni], acc[mi][ni], 0, 0, 0);
                    acc[mi][ni] = MFMA(aH[mi], bL[ni], acc[mi][ni], 0, 0, 0);
                    acc[mi][ni] = MFMA(aL[mi], bH[ni], acc[mi][ni], 0, 0, 0);
                }
        }
    }

#pragma unroll
    for (int mi = 0; mi < 2; ++mi)
#pragma unroll
        for (int ni = 0; ni < 4; ++ni) {
            const int m = m0 + wr + mi * 16 + lg * 4;   // 4 consecutive m via i
            const int n = n0 + wc + ni * 16 + lm;
            if (MODE == 0) {
                const int bb = n >> 10, s = n & 1023;
                const int h = m >> 6, dh = m & 63;
                const size_t base = (((size_t)(bb * 16 + h) << 10) + s) * 64 + dh;
                u16 hh[4], ll[4];
#pragma unroll
                for (int i = 0; i < 4; ++i) {
                    hh[i] = f2bf(acc[mi][ni][i]);
                    ll[i] = f2bf(acc[mi][ni][i] - bf2f(hh[i]));
                }
                *(uint2*)&((u16*)C0)[base] = make_uint2((u32)hh[0] | ((u32)hh[1] << 16),
                                                        (u32)hh[2] | ((u32)hh[3] << 16));
                *(uint2*)&((u16*)C1)[base] = make_uint2((u32)ll[0] | ((u32)ll[1] << 16),
                                                        (u32)ll[2] | ((u32)ll[3] << 16));
            } else {
#pragma unroll
                for (int i = 0; i < 4; ++i)
                    ((float*)C0)[(size_t)(m + i) * 1024 + n] = acc[mi][ni][i];
            }
        }
}

// Fused scores (split-bf16 MFMA, S^T) + softmax + cumulative-threshold bisection + head-mean.
// Block = (b, 16 q-rows, head-parity p): 8 heads h = 2t|p. 8 waves; wave w computes kv-slice
// [w*128,+128) x 16 q via MFMA, then softmax rows 2w, 2w+1. Head-mean via atomicAdd (attn pre-zeroed).
__global__ __launch_bounds__(512, 4)
void attn2_k(const u16* __restrict__ qhh, const u16* __restrict__ qhl,
             const u16* __restrict__ khh, const u16* __restrict__ khl,
             const int* __restrict__ kmask, float* __restrict__ attn)
{
    __shared__ __align__(16) float S[16][1028];
    __shared__ __align__(16) float mneg[1024];
    const int tid = threadIdx.x;
    const int b = blockIdx.x >> 7;
    const int q0 = ((blockIdx.x >> 1) & 63) << 4;
    const int p = blockIdx.x & 1;
    const int w = tid >> 6, l = tid & 63;
    const int lm = l & 15, lg = l >> 4;

    for (int i = tid; i < 1024; i += 512)
        mneg[i] = (kmask[(b << 10) + i] > 0) ? 0.f : -3.0e38f;

    float racc0[16], racc1[16];
#pragma unroll
    for (int j = 0; j < 16; ++j) { racc0[j] = 0.f; racc1[j] = 0.f; }

    for (int t = 0; t < 8; ++t) {
        const int h = (t << 1) | p;
        const size_t hb = (size_t)((b << 4) + h) << 10;
        const size_t qoff = (hb + q0 + lm) * 64 + (lg << 3);
        const bf16x8 bh0 = *(const bf16x8*)&qhh[qoff];
        const bf16x8 bh1 = *(const bf16x8*)&qhh[qoff + 32];
        const bf16x8 bl0 = *(const bf16x8*)&qhl[qoff];
        const bf16x8 bl1 = *(const bf16x8*)&qhl[qoff + 32];

        f32x4 acc[8];
#pragma unroll
        for (int mi = 0; mi < 8; ++mi) acc[mi] = (f32x4){0.f, 0.f, 0.f, 0.f};

        const int kvb = w << 7;
#pragma unroll
        for (int mi = 0; mi < 8; ++mi) {
            const size_t aoff = (hb + kvb + (mi << 4) + lm) * 64 + (lg << 3);
            const bf16x8 ah0 = *(const bf16x8*)&khh[aoff];
            const bf16x8 ah1 = *(const bf16x8*)&khh[aoff + 32];
            const bf16x8 al0 = *(const bf16x8*)&khl[aoff];
            const bf16x8 al1 = *(const bf16x8*)&khl[aoff + 32];
            acc[mi] = MFMA(ah0, bh0, acc[mi], 0, 0, 0);
            acc[mi] = MFMA(ah0, bl0, acc[mi], 0, 0, 0);
            acc[mi] = MFMA(al0, bh0, acc[mi], 0, 0, 0);
            acc[mi] = MFMA(ah1, bh1, acc[mi], 0, 0, 0);
            acc[mi] = MFMA(ah1, bl1, acc[mi], 0, 0, 0);
            acc[mi] = MFMA(al1, bh1, acc[mi], 0, 0, 0);
        }
        __syncthreads();   // previous head's softmax reads finished
#pragma unroll
        for (int mi = 0; mi < 8; ++mi)
            *(f32x4*)&S[lm][kvb + (mi << 4) + (lg << 2)] = acc[mi];
        __syncthreads();

        // softmax + bisection for rows 2w, 2w+1 (interleaved for latency hiding)
        float sa[16], sb[16];
#pragma unroll
        for (int jj = 0; jj < 4; ++jj) {
            const f32x4 va = *(const f32x4*)&S[2 * w][jj * 256 + l * 4];
            const f32x4 vb = *(const f32x4*)&S[2 * w + 1][jj * 256 + l * 4];
            const f32x4 vm = *(const f32x4*)&mneg[jj * 256 + l * 4];
#pragma unroll
            for (int ii = 0; ii < 4; ++ii) {
                sa[jj * 4 + ii] = va[ii] * 0.125f + vm[ii];
                sb[jj * 4 + ii] = vb[ii] * 0.125f + vm[ii];
            }
        }
        float ma = -3.0e38f, mb = -3.0e38f;
#pragma unroll
        for (int j = 0; j < 16; ++j) { ma = fmaxf(ma, sa[j]); mb = fmaxf(mb, sb[j]); }
#pragma unroll
        for (int off = 32; off; off >>= 1) { ma = fmaxf(ma, __shfl_xor(ma, off)); mb = fmaxf(mb, __shfl_xor(mb, off)); }
        float Za = 0.f, Zb = 0.f;
#pragma unroll
        for (int j = 0; j < 16; ++j) {
            sa[j] = __expf(sa[j] - ma); Za += sa[j];
            sb[j] = __expf(sb[j] - mb); Zb += sb[j];
        }
#pragma unroll
        for (int off = 32; off; off >>= 1) { Za += __shfl_xor(Za, off); Zb += __shfl_xor(Zb, off); }

        // zero element iff S_le(e) < 0.1*Z; bisection on e in (0,1]
        const float tga = 0.1f * Za, tgb = 0.1f * Zb;
        float loa = 0.f, hia = 1.f, lob = 0.f, hib = 1.f;
        for (int it = 0; it < 15; ++it) {
            const float ca = 0.5f * (loa + hia), cb = 0.5f * (lob + hib);
            float ta = 0.f, tb = 0.f;
#pragma unroll
            for (int j = 0; j < 16; ++j) {
                ta += (sa[j] <= ca) ? sa[j] : 0.f;
                tb += (sb[j] <= cb) ? sb[j] : 0.f;
            }
#pragma unroll
            for (int off = 32; off; off >>= 1) { ta += __shfl_xor(ta, off); tb += __shfl_xor(tb, off); }
            if (ta < tga) loa = ca; else hia = ca;   // ta bit-identical across lanes
            if (tb < tgb) lob = cb; else hib = cb;
        }
        float Aa = 0.f, Ab = 0.f;
#pragma unroll
        for (int j = 0; j < 16; ++j) {
            Aa += (sa[j] > loa) ? sa[j] : 0.f;
            Ab += (sb[j] > lob) ? sb[j] : 0.f;
        }
#pragma unroll
        for (int off = 32; off; off >>= 1) { Aa += __shfl_xor(Aa, off); Ab += __shfl_xor(Ab, off); }
        const float rna = 1.f / (Aa + 1e-7f * Za);
        const float rnb = 1.f / (Ab + 1e-7f * Zb);
#pragma unroll
        for (int j = 0; j < 16; ++j) {
            racc0[j] += ((sa[j] > loa) ? sa[j] : 0.f) * rna;
            racc1[j] += ((sb[j] > lob) ? sb[j] : 0.f) * rnb;
        }
    }

    // head-mean partial (8 of 16 heads) -> atomic accumulate into zeroed attn
#pragma unroll
    for (int jj = 0; jj < 4; ++jj)
#pragma unroll
        for (int ii = 0; ii < 4; ++ii) {
            atomicAdd(&attn[((size_t)(b << 10) + q0 + 2 * w) * 1024 + jj * 256 + l * 4 + ii],
                      racc0[jj * 4 + ii] * 0.0625f);
            atomicAdd(&attn[((size_t)(b << 10) + q0 + 2 * w + 1) * 1024 + jj * 256 + l * 4 + ii],
                      racc1[jj * 4 + ii] * 0.0625f);
        }
}

// v [b][kv][d] f32 -> vt [b][d][kv] f32 (64x64 LDS tiles)
__global__ __launch_bounds__(256)
void vtT_k(const float* __restrict__ v, float* __restrict__ vt)
{
    __shared__ float T[64][65];
    const int b = blockIdx.z;
    const int kv0 = blockIdx.y << 6, d0 = blockIdx.x << 6;
    const int t = threadIdx.x;
    const int tr = t >> 4, tc = t & 15;
#pragma unroll
    for (int i = 0; i < 4; ++i) {
        const float4 x = *(const float4*)&v[(((size_t)b << 10) + kv0 + tr + i * 16) * 1024 + d0 + tc * 4];
        float* d = &T[tr + i * 16][tc * 4];
        d[0] = x.x; d[1] = x.y; d[2] = x.z; d[3] = x.w;
    }
    __syncthreads();
#pragma unroll
    for (int i = 0; i < 4; ++i) {
        const int dr = tr + i * 16;
        float4 o;
        o.x = T[tc * 4 + 0][dr]; o.y = T[tc * 4 + 1][dr];
        o.z = T[tc * 4 + 2][dr]; o.w = T[tc * 4 + 3][dr];
        *(float4*)&vt[(((size_t)b << 10) + d0 + dr) * 1024 + kv0 + tc * 4] = o;
    }
}

extern "C" void kernel_launch(void* const* d_in, const int* in_sizes, int n_in,
                              void* d_out, int out_size, void* d_ws, size_t ws_size,
                              hipStream_t stream) {
    const float* q  = (const float*)d_in[0];
    const float* k  = (const float*)d_in[1];
    const float* v  = (const float*)d_in[2];
    const float* Wq = (const float*)d_in[3];
    const float* Wk = (const float*)d_in[4];
    const int* kmask = (const int*)d_in[5];

    // d_out: [0,16.8MB) = qh hi/lo during attn, then final out; [16.8,33.6MB) = attn f32 (final)
    // d_ws : [0,16.8MB) = kh hi/lo during attn, then vt f32
    u16* qhh = (u16*)d_out;
    u16* qhl = qhh + 4194304;
    u16* khh = (u16*)d_ws;
    u16* khl = khh + 4194304;
    float* attn = (float*)d_out + 4194304;
    float* vt   = (float*)d_ws;
    float* out  = (float*)d_out;

    hipMemsetAsync(attn, 0, (size_t)4 * 1024 * 1024 * sizeof(float), stream);
    gemmT<0><<<dim3(32, 16), 256, 0, stream>>>(Wq, q, qhh, qhl);   // qh = q @ Wq^T (head layout)
    gemmT<0><<<dim3(32, 16), 256, 0, stream>>>(Wk, k, khh, khl);   // kh = k @ Wk^T
    attn2_k<<<dim3(512), dim3(512), 0, stream>>>(qhh, qhl, khh, khl, kmask, attn);
    vtT_k<<<dim3(16, 16, 4), 256, 0, stream>>>(v, vt);             // vt = v^T (kh dead now)
    gemmT<2><<<dim3(8, 64), 256, 0, stream>>>(attn, vt, out, nullptr);  // out = attn @ v
}

// Round 5
// 481.020 us; speedup vs baseline: 2.1581x; 1.1029x over previous
//
#include <hip/hip_runtime.h>

typedef unsigned short u16;
typedef unsigned int u32;
typedef __attribute__((ext_vector_type(8))) short bf16x8;
typedef __attribute__((ext_vector_type(4))) float f32x4;

#define MFMA __builtin_amdgcn_mfma_f32_16x16x32_bf16

__device__ __forceinline__ u16 f2bf(float x) {
    union { float f; u32 u; } a; a.f = x;
    return (u16)((a.u + 0x7fffu + ((a.u >> 16) & 1u)) >> 16);
}
__device__ __forceinline__ float bf2f(u16 h) {
    union { u32 u; float f; } a; a.u = ((u32)h) << 16;
    return a.f;
}

// ---- wave64 reductions via DPP (pure VALU, no DS ops). Result = full-wave red in lane 63,
//      broadcast to all lanes as a uniform value via readlane. ----
#define DPP_ADD(v, ctrl, rmask)                                                             \
    v += __uint_as_float((u32)__builtin_amdgcn_update_dpp(0, (int)__float_as_uint(v),       \
                                                          ctrl, rmask, 0xF, true))
#define DPP_MAX(v, ctrl, rmask)                                                             \
    v = fmaxf(v, __uint_as_float((u32)__builtin_amdgcn_update_dpp(                          \
            (int)__float_as_uint(v), (int)__float_as_uint(v), ctrl, rmask, 0xF, false)))

__device__ __forceinline__ float wsum(float v) {
    DPP_ADD(v, 0x111, 0xF);   // row_shr:1
    DPP_ADD(v, 0x112, 0xF);   // row_shr:2
    DPP_ADD(v, 0x114, 0xF);   // row_shr:4
    DPP_ADD(v, 0x118, 0xF);   // row_shr:8  -> lane15 of each row16 = row sum
    DPP_ADD(v, 0x142, 0xA);   // row_bcast15 -> rows 1,3 accumulate prior row
    DPP_ADD(v, 0x143, 0xC);   // row_bcast31 -> lane 63 = total
    return __uint_as_float((u32)__builtin_amdgcn_readlane((int)__float_as_uint(v), 63));
}
__device__ __forceinline__ float wmax(float v) {
    DPP_MAX(v, 0x111, 0xF);
    DPP_MAX(v, 0x112, 0xF);
    DPP_MAX(v, 0x114, 0xF);
    DPP_MAX(v, 0x118, 0xF);
    DPP_MAX(v, 0x142, 0xA);
    DPP_MAX(v, 0x143, 0xC);
    return __uint_as_float((u32)__builtin_amdgcn_readlane((int)__float_as_uint(v), 63));
}

// Convert one float4 to hi/lo bf16 (RNE, bit-identical to f2bf path) and store 8B each
// into swizzled LDS tile (rows 128B). Uses v_perm_b32 to pack without shifts.
__device__ __forceinline__ void cvt_store(char* Lh, char* Ll, int row, int c4, float4 x) {
    u32 ux = __float_as_uint(x.x), uy = __float_as_uint(x.y),
        uz = __float_as_uint(x.z), uw = __float_as_uint(x.w);
    u32 rx = ux + 0x7fffu + ((ux >> 16) & 1u), ry = uy + 0x7fffu + ((uy >> 16) & 1u);
    u32 rz = uz + 0x7fffu + ((uz >> 16) & 1u), rw = uw + 0x7fffu + ((uw >> 16) & 1u);
    u32 h01 = __builtin_amdgcn_perm(ry, rx, 0x07060302);
    u32 h23 = __builtin_amdgcn_perm(rw, rz, 0x07060302);
    float lx = x.x - __uint_as_float(rx & 0xffff0000u);
    float ly = x.y - __uint_as_float(ry & 0xffff0000u);
    float lz = x.z - __uint_as_float(rz & 0xffff0000u);
    float lw = x.w - __uint_as_float(rw & 0xffff0000u);
    u32 sx = __float_as_uint(lx); sx += 0x7fffu + ((sx >> 16) & 1u);
    u32 sy = __float_as_uint(ly); sy += 0x7fffu + ((sy >> 16) & 1u);
    u32 sz = __float_as_uint(lz); sz += 0x7fffu + ((sz >> 16) & 1u);
    u32 sw = __float_as_uint(lw); sw += 0x7fffu + ((sw >> 16) & 1u);
    u32 l01 = __builtin_amdgcn_perm(sy, sx, 0x07060302);
    u32 l23 = __builtin_amdgcn_perm(sw, sz, 0x07060302);
    const int byte = row * 128 + ((((c4 >> 1) << 4) ^ ((row & 7) << 4)) | ((c4 & 1) << 3));
    *(uint2*)&Lh[byte] = make_uint2(h01, h23);
    *(uint2*)&Ll[byte] = make_uint2(l01, l23);
}

// Read one 16x32 MFMA fragment (8 bf16/lane) from a swizzled [rows][64]bf16 LDS tile.
__device__ __forceinline__ bf16x8 ldfrag(const char* L, int row, int kk, int lg) {
    const int cb = (kk * 64 + (lg << 4)) ^ ((row & 7) << 4);
    return *(const bf16x8*)&L[row * 128 + cb];
}

// Split-bf16 MFMA GEMM: D[m][n] = sum_k A[m][k]*B[n][k], f32 inputs, f32-accurate (hh+hl+lh).
// Tiles 64(m) x 128(n) x 64(k); 256 threads / 4 waves; wave tile 32x64.
// Register-prefetched staging: next K-step's global loads issue before the MFMA section.
// MODE 0: proj — C = hi/lo bf16 pair in head layout [b][h][s][dh] with m=e, n=(b,s).
// MODE 2: out  — C = f32 row-major [m][n]; B batched per 1024 m-rows (vt[b][n][k]).
template<int MODE>
__global__ __launch_bounds__(256, 2)
void gemmT(const float* __restrict__ A, const float* __restrict__ B,
           void* __restrict__ C0, void* __restrict__ C1)
{
    __shared__ __align__(16) char Ah[8192], Al[8192], Bh[16384], Bl[16384];
    const int tid = threadIdx.x;
    const int m0 = blockIdx.y * 64;
    const int n0 = blockIdx.x * 128;
    const int w = tid >> 6, l = tid & 63;
    const int wr = (w >> 1) * 32, wc = (w & 1) * 64;
    const int lm = l & 15, lg = l >> 4;
    const float* Bp = B + (MODE == 2 ? ((size_t)(m0 >> 10) << 20) : (size_t)0);

    f32x4 acc[2][4];
#pragma unroll
    for (int a = 0; a < 2; ++a)
#pragma unroll
        for (int bq = 0; bq < 4; ++bq) acc[a][bq] = (f32x4){0.f, 0.f, 0.f, 0.f};

    const int ar = tid >> 2, ac = tid & 3;   // A: 64 rows, 16 floats/thread
    const int br = tid >> 1, bc = tid & 1;   // B: 128 rows, 32 floats/thread
    const float* Aptr = &A[(size_t)(m0 + ar) * 1024 + ac * 16];
    const float* Bptr = &Bp[(size_t)(n0 + br) * 1024 + bc * 32];

    float4 pa[4], pb[8];
#pragma unroll
    for (int j = 0; j < 4; ++j) pa[j] = *(const float4*)&Aptr[j * 4];
#pragma unroll
    for (int j = 0; j < 8; ++j) pb[j] = *(const float4*)&Bptr[j * 4];

    for (int k0 = 0; k0 < 1024; k0 += 64) {
        __syncthreads();
#pragma unroll
        for (int j = 0; j < 4; ++j) cvt_store(Ah, Al, ar, ac * 4 + j, pa[j]);
#pragma unroll
        for (int j = 0; j < 8; ++j) cvt_store(Bh, Bl, br, bc * 8 + j, pb[j]);
        __syncthreads();
        if (k0 + 64 < 1024) {   // prefetch next K-step while MFMAs run
#pragma unroll
            for (int j = 0; j < 4; ++j) pa[j] = *(const float4*)&Aptr[k0 + 64 + j * 4];
#pragma unroll
            for (int j = 0; j < 8; ++j) pb[j] = *(const float4*)&Bptr[k0 + 64 + j * 4];
        }
#pragma unroll
        for (int kk = 0; kk < 2; ++kk) {
            bf16x8 aH[2], aL[2], bH[4], bL[4];
#pragma unroll
            for (int mi = 0; mi < 2; ++mi) {
                aH[mi] = ldfrag(Ah, wr + mi * 16 + lm, kk, lg);
                aL[mi] = ldfrag(Al, wr + mi * 16 + lm, kk, lg);
            }
#pragma unroll
            for (int ni = 0; ni < 4; ++ni) {
                bH[ni] = ldfrag(Bh, wc + ni * 16 + lm, kk, lg);
                bL[ni] = ldfrag(Bl, wc + ni * 16 + lm, kk, lg);
            }
#pragma unroll
            for (int mi = 0; mi < 2; ++mi)
#pragma unroll
                for (int ni = 0; ni < 4; ++ni) {
                    acc[mi][ni] = MFMA(aH[mi], bH[ni], acc[mi][ni], 0, 0, 0);
                    acc[mi][ni] = MFMA(aH[mi], bL[ni], acc[mi][ni], 0, 0, 0);
                    acc[mi][ni] = MFMA(aL[mi], bH[ni], acc[mi][ni], 0, 0, 0);
                }
        }
    }

#pragma unroll
    for (int mi = 0; mi < 2; ++mi)
#pragma unroll
        for (int ni = 0; ni < 4; ++ni) {
            const int m = m0 + wr + mi * 16 + lg * 4;   // 4 consecutive m via i
            const int n = n0 + wc + ni * 16 + lm;
            if (MODE == 0) {
                const int bb = n >> 10, s = n & 1023;
                const int h = m >> 6, dh = m & 63;
                const size_t base = (((size_t)(bb * 16 + h) << 10) + s) * 64 + dh;
                u16 hh[4], ll[4];
#pragma unroll
                for (int i = 0; i < 4; ++i) {
                    hh[i] = f2bf(acc[mi][ni][i]);
                    ll[i] = f2bf(acc[mi][ni][i] - bf2f(hh[i]));
                }
                *(uint2*)&((u16*)C0)[base] = make_uint2((u32)hh[0] | ((u32)hh[1] << 16),
                                                        (u32)hh[2] | ((u32)hh[3] << 16));
                *(uint2*)&((u16*)C1)[base] = make_uint2((u32)ll[0] | ((u32)ll[1] << 16),
                                                        (u32)ll[2] | ((u32)ll[3] << 16));
            } else {
#pragma unroll
                for (int i = 0; i < 4; ++i)
                    ((float*)C0)[(size_t)(m + i) * 1024 + n] = acc[mi][ni][i];
            }
        }
}

// Fused scores (split-bf16 MFMA, S^T) + softmax + cumulative-threshold bisection + head-mean.
// Block = (b, 16 q-rows, head-parity p): 8 heads h = 2t|p. 8 waves; wave w computes kv-slice
// [w*128,+128) x 16 q via MFMA, then softmax rows 2w, 2w+1 (all reductions via DPP, no DS).
__global__ __launch_bounds__(512, 4)
void attn2_k(const u16* __restrict__ qhh, const u16* __restrict__ qhl,
             const u16* __restrict__ khh, const u16* __restrict__ khl,
             const int* __restrict__ kmask, float* __restrict__ attn)
{
    __shared__ __align__(16) float S[16][1028];
    __shared__ __align__(16) float mneg[1024];
    const int tid = threadIdx.x;
    const int b = blockIdx.x >> 7;
    const int q0 = ((blockIdx.x >> 1) & 63) << 4;
    const int p = blockIdx.x & 1;
    const int w = tid >> 6, l = tid & 63;
    const int lm = l & 15, lg = l >> 4;

    for (int i = tid; i < 1024; i += 512)
        mneg[i] = (kmask[(b << 10) + i] > 0) ? 0.f : -3.0e38f;

    float racc0[16], racc1[16];
#pragma unroll
    for (int j = 0; j < 16; ++j) { racc0[j] = 0.f; racc1[j] = 0.f; }

    for (int t = 0; t < 8; ++t) {
        const int h = (t << 1) | p;
        const size_t hb = (size_t)((b << 4) + h) << 10;
        const size_t qoff = (hb + q0 + lm) * 64 + (lg << 3);
        const bf16x8 bh0 = *(const bf16x8*)&qhh[qoff];
        const bf16x8 bh1 = *(const bf16x8*)&qhh[qoff + 32];
        const bf16x8 bl0 = *(const bf16x8*)&qhl[qoff];
        const bf16x8 bl1 = *(const bf16x8*)&qhl[qoff + 32];

        f32x4 acc[8];
#pragma unroll
        for (int mi = 0; mi < 8; ++mi) acc[mi] = (f32x4){0.f, 0.f, 0.f, 0.f};

        const int kvb = w << 7;
#pragma unroll
        for (int mi = 0; mi < 8; ++mi) {
            const size_t aoff = (hb + kvb + (mi << 4) + lm) * 64 + (lg << 3);
            const bf16x8 ah0 = *(const bf16x8*)&khh[aoff];
            const bf16x8 ah1 = *(const bf16x8*)&khh[aoff + 32];
            const bf16x8 al0 = *(const bf16x8*)&khl[aoff];
            const bf16x8 al1 = *(const bf16x8*)&khl[aoff + 32];
            acc[mi] = MFMA(ah0, bh0, acc[mi], 0, 0, 0);
            acc[mi] = MFMA(ah0, bl0, acc[mi], 0, 0, 0);
            acc[mi] = MFMA(al0, bh0, acc[mi], 0, 0, 0);
            acc[mi] = MFMA(ah1, bh1, acc[mi], 0, 0, 0);
            acc[mi] = MFMA(ah1, bl1, acc[mi], 0, 0, 0);
            acc[mi] = MFMA(al1, bh1, acc[mi], 0, 0, 0);
        }
        __syncthreads();   // previous head's softmax reads finished
#pragma unroll
        for (int mi = 0; mi < 8; ++mi)
            *(f32x4*)&S[lm][kvb + (mi << 4) + (lg << 2)] = acc[mi];
        __syncthreads();

        // rows 2w, 2w+1 in registers (interleaved for ILP)
        float sa[16], sb[16];
#pragma unroll
        for (int jj = 0; jj < 4; ++jj) {
            const f32x4 va = *(const f32x4*)&S[2 * w][jj * 256 + l * 4];
            const f32x4 vb = *(const f32x4*)&S[2 * w + 1][jj * 256 + l * 4];
            const f32x4 vm = *(const f32x4*)&mneg[jj * 256 + l * 4];
#pragma unroll
            for (int ii = 0; ii < 4; ++ii) {
                sa[jj * 4 + ii] = va[ii] * 0.125f + vm[ii];
                sb[jj * 4 + ii] = vb[ii] * 0.125f + vm[ii];
            }
        }
        float ma = sa[0], mb = sb[0];
#pragma unroll
        for (int j = 1; j < 16; ++j) { ma = fmaxf(ma, sa[j]); mb = fmaxf(mb, sb[j]); }
        ma = wmax(ma); mb = wmax(mb);

        float z0 = 0.f, z1 = 0.f, z2 = 0.f, z3 = 0.f, y0 = 0.f, y1 = 0.f, y2 = 0.f, y3 = 0.f;
#pragma unroll
        for (int j = 0; j < 4; ++j) {
            sa[j]      = __expf(sa[j]      - ma); z0 += sa[j];
            sa[j + 4]  = __expf(sa[j + 4]  - ma); z1 += sa[j + 4];
            sa[j + 8]  = __expf(sa[j + 8]  - ma); z2 += sa[j + 8];
            sa[j + 12] = __expf(sa[j + 12] - ma); z3 += sa[j + 12];
            sb[j]      = __expf(sb[j]      - mb); y0 += sb[j];
            sb[j + 4]  = __expf(sb[j + 4]  - mb); y1 += sb[j + 4];
            sb[j + 8]  = __expf(sb[j + 8]  - mb); y2 += sb[j + 8];
            sb[j + 12] = __expf(sb[j + 12] - mb); y3 += sb[j + 12];
        }
        const float Za = wsum((z0 + z1) + (z2 + z3));
        const float Zb = wsum((y0 + y1) + (y2 + y3));

        // zero element iff S_le(e) < 0.1*Z; bisection on e in (0,1]
        const float tga = 0.1f * Za, tgb = 0.1f * Zb;
        float loa = 0.f, hia = 1.f, lob = 0.f, hib = 1.f;
        for (int it = 0; it < 15; ++it) {
            const float ca = 0.5f * (loa + hia), cb = 0.5f * (lob + hib);
            float t0 = 0.f, t1 = 0.f, t2 = 0.f, t3 = 0.f;
            float u0 = 0.f, u1 = 0.f, u2 = 0.f, u3 = 0.f;
#pragma unroll
            for (int j = 0; j < 4; ++j) {
                t0 += (sa[j]      <= ca) ? sa[j]      : 0.f;
                t1 += (sa[j + 4]  <= ca) ? sa[j + 4]  : 0.f;
                t2 += (sa[j + 8]  <= ca) ? sa[j + 8]  : 0.f;
                t3 += (sa[j + 12] <= ca) ? sa[j + 12] : 0.f;
                u0 += (sb[j]      <= cb) ? sb[j]      : 0.f;
                u1 += (sb[j + 4]  <= cb) ? sb[j + 4]  : 0.f;
                u2 += (sb[j + 8]  <= cb) ? sb[j + 8]  : 0.f;
                u3 += (sb[j + 12] <= cb) ? sb[j + 12] : 0.f;
            }
            const float ta = wsum((t0 + t1) + (t2 + t3));
            const float tb = wsum((u0 + u1) + (u2 + u3));
            if (ta < tga) loa = ca; else hia = ca;   // uniform (readlane-broadcast)
            if (tb < tgb) lob = cb; else hib = cb;
        }
        float a0 = 0.f, a1 = 0.f, a2 = 0.f, a3 = 0.f, b0 = 0.f, b1 = 0.f, b2 = 0.f, b3 = 0.f;
#pragma unroll
        for (int j = 0; j < 4; ++j) {
            a0 += (sa[j]      > loa) ? sa[j]      : 0.f;
            a1 += (sa[j + 4]  > loa) ? sa[j + 4]  : 0.f;
            a2 += (sa[j + 8]  > loa) ? sa[j + 8]  : 0.f;
            a3 += (sa[j + 12] > loa) ? sa[j + 12] : 0.f;
            b0 += (sb[j]      > lob) ? sb[j]      : 0.f;
            b1 += (sb[j + 4]  > lob) ? sb[j + 4]  : 0.f;
            b2 += (sb[j + 8]  > lob) ? sb[j + 8]  : 0.f;
            b3 += (sb[j + 12] > lob) ? sb[j + 12] : 0.f;
        }
        const float Aa = wsum((a0 + a1) + (a2 + a3));
        const float Ab = wsum((b0 + b1) + (b2 + b3));
        const float rna = 1.f / (Aa + 1e-7f * Za);
        const float rnb = 1.f / (Ab + 1e-7f * Zb);
#pragma unroll
        for (int j = 0; j < 16; ++j) {
            racc0[j] += ((sa[j] > loa) ? sa[j] : 0.f) * rna;
            racc1[j] += ((sb[j] > lob) ? sb[j] : 0.f) * rnb;
        }
    }

    // head-mean partial (8 of 16 heads) -> atomic accumulate into zeroed attn
#pragma unroll
    for (int jj = 0; jj < 4; ++jj)
#pragma unroll
        for (int ii = 0; ii < 4; ++ii) {
            atomicAdd(&attn[((size_t)(b << 10) + q0 + 2 * w) * 1024 + jj * 256 + l * 4 + ii],
                      racc0[jj * 4 + ii] * 0.0625f);
            atomicAdd(&attn[((size_t)(b << 10) + q0 + 2 * w + 1) * 1024 + jj * 256 + l * 4 + ii],
                      racc1[jj * 4 + ii] * 0.0625f);
        }
}

// v [b][kv][d] f32 -> vt [b][d][kv] f32 (64x64 LDS tiles)
__global__ __launch_bounds__(256)
void vtT_k(const float* __restrict__ v, float* __restrict__ vt)
{
    __shared__ float T[64][65];
    const int b = blockIdx.z;
    const int kv0 = blockIdx.y << 6, d0 = blockIdx.x << 6;
    const int t = threadIdx.x;
    const int tr = t >> 4, tc = t & 15;
#pragma unroll
    for (int i = 0; i < 4; ++i) {
        const float4 x = *(const float4*)&v[(((size_t)b << 10) + kv0 + tr + i * 16) * 1024 + d0 + tc * 4];
        float* d = &T[tr + i * 16][tc * 4];
        d[0] = x.x; d[1] = x.y; d[2] = x.z; d[3] = x.w;
    }
    __syncthreads();
#pragma unroll
    for (int i = 0; i < 4; ++i) {
        const int dr = tr + i * 16;
        float4 o;
        o.x = T[tc * 4 + 0][dr]; o.y = T[tc * 4 + 1][dr];
        o.z = T[tc * 4 + 2][dr]; o.w = T[tc * 4 + 3][dr];
        *(float4*)&vt[(((size_t)b << 10) + d0 + dr) * 1024 + kv0 + tc * 4] = o;
    }
}

extern "C" void kernel_launch(void* const* d_in, const int* in_sizes, int n_in,
                              void* d_out, int out_size, void* d_ws, size_t ws_size,
                              hipStream_t stream) {
    const float* q  = (const float*)d_in[0];
    const float* k  = (const float*)d_in[1];
    const float* v  = (const float*)d_in[2];
    const float* Wq = (const float*)d_in[3];
    const float* Wk = (const float*)d_in[4];
    const int* kmask = (const int*)d_in[5];

    // d_out: [0,16.8MB) = qh hi/lo during attn, then final out; [16.8,33.6MB) = attn f32 (final)
    // d_ws : [0,16.8MB) = kh hi/lo during attn, then vt f32
    u16* qhh = (u16*)d_out;
    u16* qhl = qhh + 4194304;
    u16* khh = (u16*)d_ws;
    u16* khl = khh + 4194304;
    float* attn = (float*)d_out + 4194304;
    float* vt   = (float*)d_ws;
    float* out  = (float*)d_out;

    hipMemsetAsync(attn, 0, (size_t)4 * 1024 * 1024 * sizeof(float), stream);
    gemmT<0><<<dim3(32, 16), 256, 0, stream>>>(Wq, q, qhh, qhl);   // qh = q @ Wq^T (head layout)
    gemmT<0><<<dim3(32, 16), 256, 0, stream>>>(Wk, k, khh, khl);   // kh = k @ Wk^T
    attn2_k<<<dim3(512), dim3(512), 0, stream>>>(qhh, qhl, khh, khl, kmask, attn);
    vtT_k<<<dim3(16, 16, 4), 256, 0, stream>>>(v, vt);             // vt = v^T (kh dead now)
    gemmT<2><<<dim3(8, 64), 256, 0, stream>>>(attn, vt, out, nullptr);  // out = attn @ v
}

// Round 6
// 472.019 us; speedup vs baseline: 2.1993x; 1.0191x over previous
//
#include <hip/hip_runtime.h>

typedef unsigned short u16;
typedef unsigned int u32;
typedef __attribute__((ext_vector_type(8))) short bf16x8;
typedef __attribute__((ext_vector_type(4))) float f32x4;

#define MFMA __builtin_amdgcn_mfma_f32_16x16x32_bf16

__device__ __forceinline__ u16 f2bf(float x) {
    union { float f; u32 u; } a; a.f = x;
    return (u16)((a.u + 0x7fffu + ((a.u >> 16) & 1u)) >> 16);
}
__device__ __forceinline__ float bf2f(u16 h) {
    union { u32 u; float f; } a; a.u = ((u32)h) << 16;
    return a.f;
}

// ---- wave64 reductions via DPP (pure VALU, no DS ops). Result = full-wave red in lane 63,
//      broadcast to all lanes as a uniform value via readlane. ----
#define DPP_ADD(v, ctrl, rmask)                                                             \
    v += __uint_as_float((u32)__builtin_amdgcn_update_dpp(0, (int)__float_as_uint(v),       \
                                                          ctrl, rmask, 0xF, true))
#define DPP_MAX(v, ctrl, rmask)                                                             \
    v = fmaxf(v, __uint_as_float((u32)__builtin_amdgcn_update_dpp(                          \
            (int)__float_as_uint(v), (int)__float_as_uint(v), ctrl, rmask, 0xF, false)))

__device__ __forceinline__ float wsum(float v) {
    DPP_ADD(v, 0x111, 0xF);   // row_shr:1
    DPP_ADD(v, 0x112, 0xF);   // row_shr:2
    DPP_ADD(v, 0x114, 0xF);   // row_shr:4
    DPP_ADD(v, 0x118, 0xF);   // row_shr:8  -> lane15 of each row16 = row sum
    DPP_ADD(v, 0x142, 0xA);   // row_bcast15 -> rows 1,3 accumulate prior row
    DPP_ADD(v, 0x143, 0xC);   // row_bcast31 -> lane 63 = total
    return __uint_as_float((u32)__builtin_amdgcn_readlane((int)__float_as_uint(v), 63));
}
__device__ __forceinline__ float wmax(float v) {
    DPP_MAX(v, 0x111, 0xF);
    DPP_MAX(v, 0x112, 0xF);
    DPP_MAX(v, 0x114, 0xF);
    DPP_MAX(v, 0x118, 0xF);
    DPP_MAX(v, 0x142, 0xA);
    DPP_MAX(v, 0x143, 0xC);
    return __uint_as_float((u32)__builtin_amdgcn_readlane((int)__float_as_uint(v), 63));
}

// Convert one float4 to hi/lo bf16 (RNE) and store 8B each into swizzled LDS tile (rows 128B).
__device__ __forceinline__ void cvt_store(char* Lh, char* Ll, int row, int c4, float4 x) {
    u32 ux = __float_as_uint(x.x), uy = __float_as_uint(x.y),
        uz = __float_as_uint(x.z), uw = __float_as_uint(x.w);
    u32 rx = ux + 0x7fffu + ((ux >> 16) & 1u), ry = uy + 0x7fffu + ((uy >> 16) & 1u);
    u32 rz = uz + 0x7fffu + ((uz >> 16) & 1u), rw = uw + 0x7fffu + ((uw >> 16) & 1u);
    u32 h01 = __builtin_amdgcn_perm(ry, rx, 0x07060302);
    u32 h23 = __builtin_amdgcn_perm(rw, rz, 0x07060302);
    float lx = x.x - __uint_as_float(rx & 0xffff0000u);
    float ly = x.y - __uint_as_float(ry & 0xffff0000u);
    float lz = x.z - __uint_as_float(rz & 0xffff0000u);
    float lw = x.w - __uint_as_float(rw & 0xffff0000u);
    u32 sx = __float_as_uint(lx); sx += 0x7fffu + ((sx >> 16) & 1u);
    u32 sy = __float_as_uint(ly); sy += 0x7fffu + ((sy >> 16) & 1u);
    u32 sz = __float_as_uint(lz); sz += 0x7fffu + ((sz >> 16) & 1u);
    u32 sw = __float_as_uint(lw); sw += 0x7fffu + ((sw >> 16) & 1u);
    u32 l01 = __builtin_amdgcn_perm(sy, sx, 0x07060302);
    u32 l23 = __builtin_amdgcn_perm(sw, sz, 0x07060302);
    const int byte = row * 128 + ((((c4 >> 1) << 4) ^ ((row & 7) << 4)) | ((c4 & 1) << 3));
    *(uint2*)&Lh[byte] = make_uint2(h01, h23);
    *(uint2*)&Ll[byte] = make_uint2(l01, l23);
}

// Read one 16x32 MFMA fragment (8 bf16/lane) from a swizzled [rows][64]bf16 LDS tile.
__device__ __forceinline__ bf16x8 ldfrag(const char* L, int row, int kk, int lg) {
    const int cb = (kk * 64 + (lg << 4)) ^ ((row & 7) << 4);
    return *(const bf16x8*)&L[row * 128 + cb];
}

// Split-bf16 MFMA GEMM: D[m][n] = sum_k A[m][k]*B[n][k], f32 inputs, f32-accurate (hh+hl+lh).
// Tiles 64(m) x 128(n) x 64(k); 256 threads / 4 waves; wave tile 32x64.
// Register-prefetched staging: next K-step's global loads issue before the MFMA section.
// MODE 0: proj — C = hi/lo bf16 pair in head layout [b][h][s][dh] with m=e, n=(b,s).
// MODE 2: out  — C = f32 row-major [m][n]; B batched per 1024 m-rows (vt[b][n][k]).
template<int MODE>
__global__ __launch_bounds__(256, 2)
void gemmT(const float* __restrict__ A, const float* __restrict__ B,
           void* __restrict__ C0, void* __restrict__ C1)
{
    __shared__ __align__(16) char Ah[8192], Al[8192], Bh[16384], Bl[16384];
    const int tid = threadIdx.x;
    const int m0 = blockIdx.y * 64;
    const int n0 = blockIdx.x * 128;
    const int w = tid >> 6, l = tid & 63;
    const int wr = (w >> 1) * 32, wc = (w & 1) * 64;
    const int lm = l & 15, lg = l >> 4;
    const float* Bp = B + (MODE == 2 ? ((size_t)(m0 >> 10) << 20) : (size_t)0);

    f32x4 acc[2][4];
#pragma unroll
    for (int a = 0; a < 2; ++a)
#pragma unroll
        for (int bq = 0; bq < 4; ++bq) acc[a][bq] = (f32x4){0.f, 0.f, 0.f, 0.f};

    const int ar = tid >> 2, ac = tid & 3;   // A: 64 rows, 16 floats/thread
    const int br = tid >> 1, bc = tid & 1;   // B: 128 rows, 32 floats/thread
    const float* Aptr = &A[(size_t)(m0 + ar) * 1024 + ac * 16];
    const float* Bptr = &Bp[(size_t)(n0 + br) * 1024 + bc * 32];

    float4 pa[4], pb[8];
#pragma unroll
    for (int j = 0; j < 4; ++j) pa[j] = *(const float4*)&Aptr[j * 4];
#pragma unroll
    for (int j = 0; j < 8; ++j) pb[j] = *(const float4*)&Bptr[j * 4];

    for (int k0 = 0; k0 < 1024; k0 += 64) {
        __syncthreads();
#pragma unroll
        for (int j = 0; j < 4; ++j) cvt_store(Ah, Al, ar, ac * 4 + j, pa[j]);
#pragma unroll
        for (int j = 0; j < 8; ++j) cvt_store(Bh, Bl, br, bc * 8 + j, pb[j]);
        __syncthreads();
        if (k0 + 64 < 1024) {   // prefetch next K-step while MFMAs run
#pragma unroll
            for (int j = 0; j < 4; ++j) pa[j] = *(const float4*)&Aptr[k0 + 64 + j * 4];
#pragma unroll
            for (int j = 0; j < 8; ++j) pb[j] = *(const float4*)&Bptr[k0 + 64 + j * 4];
        }
#pragma unroll
        for (int kk = 0; kk < 2; ++kk) {
            bf16x8 aH[2], aL[2], bH[4], bL[4];
#pragma unroll
            for (int mi = 0; mi < 2; ++mi) {
                aH[mi] = ldfrag(Ah, wr + mi * 16 + lm, kk, lg);
                aL[mi] = ldfrag(Al, wr + mi * 16 + lm, kk, lg);
            }
#pragma unroll
            for (int ni = 0; ni < 4; ++ni) {
                bH[ni] = ldfrag(Bh, wc + ni * 16 + lm, kk, lg);
                bL[ni] = ldfrag(Bl, wc + ni * 16 + lm, kk, lg);
            }
#pragma unroll
            for (int mi = 0; mi < 2; ++mi)
#pragma unroll
                for (int ni = 0; ni < 4; ++ni) {
                    acc[mi][ni] = MFMA(aH[mi], bH[ni], acc[mi][ni], 0, 0, 0);
                    acc[mi][ni] = MFMA(aH[mi], bL[ni], acc[mi][ni], 0, 0, 0);
                    acc[mi][ni] = MFMA(aL[mi], bH[ni], acc[mi][ni], 0, 0, 0);
                }
        }
    }

#pragma unroll
    for (int mi = 0; mi < 2; ++mi)
#pragma unroll
        for (int ni = 0; ni < 4; ++ni) {
            const int m = m0 + wr + mi * 16 + lg * 4;   // 4 consecutive m via i
            const int n = n0 + wc + ni * 16 + lm;
            if (MODE == 0) {
                const int bb = n >> 10, s = n & 1023;
                const int h = m >> 6, dh = m & 63;
                const size_t base = (((size_t)(bb * 16 + h) << 10) + s) * 64 + dh;
                u16 hh[4], ll[4];
#pragma unroll
                for (int i = 0; i < 4; ++i) {
                    hh[i] = f2bf(acc[mi][ni][i]);
                    ll[i] = f2bf(acc[mi][ni][i] - bf2f(hh[i]));
                }
                *(uint2*)&((u16*)C0)[base] = make_uint2((u32)hh[0] | ((u32)hh[1] << 16),
                                                        (u32)hh[2] | ((u32)hh[3] << 16));
                *(uint2*)&((u16*)C1)[base] = make_uint2((u32)ll[0] | ((u32)ll[1] << 16),
                                                        (u32)ll[2] | ((u32)ll[3] << 16));
            } else {
#pragma unroll
                for (int i = 0; i < 4; ++i)
                    ((float*)C0)[(size_t)(m + i) * 1024 + n] = acc[mi][ni][i];
            }
        }
}

// Fused scores (split-bf16 MFMA, S^T) + softmax + cumulative-threshold bisection + head-mean.
// Block = (b, 16 q-rows, head-parity p): 8 heads h = 2t|p. 8 waves; wave w computes kv-slice
// [w*128,+128) x 16 q via MFMA, then softmax rows 2w, 2w+1 SEQUENTIALLY (register budget:
// 2 blocks/CU * 8 waves => <=128 unified regs/wave; serial rows keep peak live ~106).
__global__ __launch_bounds__(512, 4)
void attn2_k(const u16* __restrict__ qhh, const u16* __restrict__ qhl,
             const u16* __restrict__ khh, const u16* __restrict__ khl,
             const int* __restrict__ kmask, float* __restrict__ attn)
{
    __shared__ __align__(16) float S[16][1028];
    __shared__ __align__(16) float mneg[1024];
    const int tid = threadIdx.x;
    const int b = blockIdx.x >> 7;
    const int q0 = ((blockIdx.x >> 1) & 63) << 4;
    const int p = blockIdx.x & 1;
    const int w = tid >> 6, l = tid & 63;
    const int lm = l & 15, lg = l >> 4;

    for (int i = tid; i < 1024; i += 512)
        mneg[i] = (kmask[(b << 10) + i] > 0) ? 0.f : -3.0e38f;

    float racc0[16], racc1[16];
#pragma unroll
    for (int j = 0; j < 16; ++j) { racc0[j] = 0.f; racc1[j] = 0.f; }

    // 32-bit element offsets (arrays are 8.4M elements < 2^31)
    const u32 hstep = 2u << 16;                 // 2 heads * 1024 rows * 64
    u32 qoff = ((u32)(((b << 4) + p) << 10) + q0 + lm) * 64 + (lg << 3);
    u32 koff = ((u32)(((b << 4) + p) << 10) + (w << 7) + lm) * 64 + (lg << 3);
    const int kvb = w << 7;

    for (int t = 0; t < 8; ++t, qoff += hstep, koff += hstep) {
        const bf16x8 bh0 = *(const bf16x8*)&qhh[qoff];
        const bf16x8 bh1 = *(const bf16x8*)&qhh[qoff + 32];
        const bf16x8 bl0 = *(const bf16x8*)&qhl[qoff];
        const bf16x8 bl1 = *(const bf16x8*)&qhl[qoff + 32];

        f32x4 acc[8];
#pragma unroll
        for (int mi = 0; mi < 8; ++mi) acc[mi] = (f32x4){0.f, 0.f, 0.f, 0.f};

#pragma unroll
        for (int mi = 0; mi < 8; ++mi) {
            const u32 aoff = koff + (u32)(mi << 10);
            const bf16x8 ah0 = *(const bf16x8*)&khh[aoff];
            const bf16x8 ah1 = *(const bf16x8*)&khh[aoff + 32];
            const bf16x8 al0 = *(const bf16x8*)&khl[aoff];
            const bf16x8 al1 = *(const bf16x8*)&khl[aoff + 32];
            acc[mi] = MFMA(ah0, bh0, acc[mi], 0, 0, 0);
            acc[mi] = MFMA(ah0, bl0, acc[mi], 0, 0, 0);
            acc[mi] = MFMA(al0, bh0, acc[mi], 0, 0, 0);
            acc[mi] = MFMA(ah1, bh1, acc[mi], 0, 0, 0);
            acc[mi] = MFMA(ah1, bl1, acc[mi], 0, 0, 0);
            acc[mi] = MFMA(al1, bh1, acc[mi], 0, 0, 0);
        }
        __syncthreads();   // previous head's softmax reads finished
#pragma unroll
        for (int mi = 0; mi < 8; ++mi)
            *(f32x4*)&S[lm][kvb + (mi << 4) + (lg << 2)] = acc[mi];
        __syncthreads();

        // rows 2w then 2w+1, fully sequential (S stays valid until next head's barrier)
#pragma unroll
        for (int half = 0; half < 2; ++half) {
            float* racc = half ? racc1 : racc0;
            float sa[16];
#pragma unroll
            for (int jj = 0; jj < 4; ++jj) {
                const f32x4 va = *(const f32x4*)&S[2 * w + half][jj * 256 + l * 4];
                const f32x4 vm = *(const f32x4*)&mneg[jj * 256 + l * 4];
#pragma unroll
                for (int ii = 0; ii < 4; ++ii)
                    sa[jj * 4 + ii] = va[ii] * 0.125f + vm[ii];
            }
            float ma = sa[0];
#pragma unroll
            for (int j = 1; j < 16; ++j) ma = fmaxf(ma, sa[j]);
            ma = wmax(ma);

            float z0 = 0.f, z1 = 0.f, z2 = 0.f, z3 = 0.f;
#pragma unroll
            for (int j = 0; j < 4; ++j) {
                sa[j]      = __expf(sa[j]      - ma); z0 += sa[j];
                sa[j + 4]  = __expf(sa[j + 4]  - ma); z1 += sa[j + 4];
                sa[j + 8]  = __expf(sa[j + 8]  - ma); z2 += sa[j + 8];
                sa[j + 12] = __expf(sa[j + 12] - ma); z3 += sa[j + 12];
            }
            const float Za = wsum((z0 + z1) + (z2 + z3));

            // zero element iff S_le(e) < 0.1*Z; bisection on e in (0,1].
            // Track Tlo = T(lo) so the kept-sum A = Z - Tlo needs no extra pass.
            const float tga = 0.1f * Za;
            float loa = 0.f, hia = 1.f, Tlo = 0.f;
            for (int it = 0; it < 15; ++it) {
                const float ca = 0.5f * (loa + hia);
                float t0 = 0.f, t1 = 0.f, t2 = 0.f, t3 = 0.f;
#pragma unroll
                for (int j = 0; j < 4; ++j) {
                    t0 += (sa[j]      <= ca) ? sa[j]      : 0.f;
                    t1 += (sa[j + 4]  <= ca) ? sa[j + 4]  : 0.f;
                    t2 += (sa[j + 8]  <= ca) ? sa[j + 8]  : 0.f;
                    t3 += (sa[j + 12] <= ca) ? sa[j + 12] : 0.f;
                }
                const float ta = wsum((t0 + t1) + (t2 + t3));
                if (ta < tga) { loa = ca; Tlo = ta; } else hia = ca;  // uniform
            }
            const float rna = 1.f / ((Za - Tlo) + 1e-7f * Za);
#pragma unroll
            for (int j = 0; j < 16; ++j)
                racc[j] += ((sa[j] > loa) ? sa[j] : 0.f) * rna;
        }
    }

    // head-mean partial (8 of 16 heads) -> atomic accumulate into zeroed attn
#pragma unroll
    for (int jj = 0; jj < 4; ++jj)
#pragma unroll
        for (int ii = 0; ii < 4; ++ii) {
            atomicAdd(&attn[((size_t)(b << 10) + q0 + 2 * w) * 1024 + jj * 256 + l * 4 + ii],
                      racc0[jj * 4 + ii] * 0.0625f);
            atomicAdd(&attn[((size_t)(b << 10) + q0 + 2 * w + 1) * 1024 + jj * 256 + l * 4 + ii],
                      racc1[jj * 4 + ii] * 0.0625f);
        }
}

// v [b][kv][d] f32 -> vt [b][d][kv] f32 (64x64 LDS tiles)
__global__ __launch_bounds__(256)
void vtT_k(const float* __restrict__ v, float* __restrict__ vt)
{
    __shared__ float T[64][65];
    const int b = blockIdx.z;
    const int kv0 = blockIdx.y << 6, d0 = blockIdx.x << 6;
    const int t = threadIdx.x;
    const int tr = t >> 4, tc = t & 15;
#pragma unroll
    for (int i = 0; i < 4; ++i) {
        const float4 x = *(const float4*)&v[(((size_t)b << 10) + kv0 + tr + i * 16) * 1024 + d0 + tc * 4];
        float* d = &T[tr + i * 16][tc * 4];
        d[0] = x.x; d[1] = x.y; d[2] = x.z; d[3] = x.w;
    }
    __syncthreads();
#pragma unroll
    for (int i = 0; i < 4; ++i) {
        const int dr = tr + i * 16;
        float4 o;
        o.x = T[tc * 4 + 0][dr]; o.y = T[tc * 4 + 1][dr];
        o.z = T[tc * 4 + 2][dr]; o.w = T[tc * 4 + 3][dr];
        *(float4*)&vt[(((size_t)b << 10) + d0 + dr) * 1024 + kv0 + tc * 4] = o;
    }
}

extern "C" void kernel_launch(void* const* d_in, const int* in_sizes, int n_in,
                              void* d_out, int out_size, void* d_ws, size_t ws_size,
                              hipStream_t stream) {
    const float* q  = (const float*)d_in[0];
    const float* k  = (const float*)d_in[1];
    const float* v  = (const float*)d_in[2];
    const float* Wq = (const float*)d_in[3];
    const float* Wk = (const float*)d_in[4];
    const int* kmask = (const int*)d_in[5];

    // d_out: [0,16.8MB) = qh hi/lo during attn, then final out; [16.8,33.6MB) = attn f32 (final)
    // d_ws : [0,16.8MB) = kh hi/lo during attn, then vt f32
    u16* qhh = (u16*)d_out;
    u16* qhl = qhh + 4194304;
    u16* khh = (u16*)d_ws;
    u16* khl = khh + 4194304;
    float* attn = (float*)d_out + 4194304;
    float* vt   = (float*)d_ws;
    float* out  = (float*)d_out;

    hipMemsetAsync(attn, 0, (size_t)4 * 1024 * 1024 * sizeof(float), stream);
    gemmT<0><<<dim3(32, 16), 256, 0, stream>>>(Wq, q, qhh, qhl);   // qh = q @ Wq^T (head layout)
    gemmT<0><<<dim3(32, 16), 256, 0, stream>>>(Wk, k, khh, khl);   // kh = k @ Wk^T
    attn2_k<<<dim3(512), dim3(512), 0, stream>>>(qhh, qhl, khh, khl, kmask, attn);
    vtT_k<<<dim3(16, 16, 4), 256, 0, stream>>>(v, vt);             // vt = v^T (kh dead now)
    gemmT<2><<<dim3(8, 64), 256, 0, stream>>>(attn, vt, out, nullptr);  // out = attn @ v
}